// Round 5
// baseline (774.924 us; speedup 1.0000x reference)
//
#include <hip/hip_runtime.h>
#include <hip/hip_cooperative_groups.h>

// CubicSplineUpsampling: (2,3,96,96,96) f32 -> (2,3,192,192,192) f32.
//
// out_line(192) = M * in_line(96) per axis, M = U_clamped(192x96) . W(96x96),
// banded to 28 taps at j0=c-13. Interior rows (c in [12,84)) collapse to one
// Toeplitz 2x28 stencil (rows 96/97 of M; error <=1e-4 << tol 1.56e-2,
// validated R2-R4). Edge rows use exact table rows.
//
// R5: three structurally different Y/X implementations all landed ~100 us/pass
// (pass_z: 64 MB at 0.6 TB/s effective) -> cost suspected at dispatch
// boundaries (graph-node cache flush / launch gaps), not inside kernels.
// Fuse Z/Y/X into ONE cooperative kernel with grid.sync() between phases.
// Either it collapses total dur (overhead theory) or it finally surfaces as
// the top-1 dispatch with full counters (attribution). Fallback: 3 separate
// kernels sharing the same device bodies if cooperative launch is refused.

namespace cg = cooperative_groups;

#define TAPS 28

__device__ double g_Wd[96 * 96];
__device__ alignas(16) float g_Mb[192 * TAPS];            // [i][t] row-major
__device__ alignas(16) float g_bufA[6 * 96 * 96 * 192];   // after Z
__device__ alignas(16) float g_bufB[6 * 96 * 192 * 192];  // after Y

__device__ __forceinline__ int clamp96(int j) { return j < 0 ? 0 : (j > 95 ? 95 : j); }

__global__ void compute_Wd_kernel(double* __restrict__ Wd) {
    int j = threadIdx.x;
    if (j >= 96) return;
    const double p = -0.26794919243112270647253365849413;  // sqrt(3)-2
    double c[96];
    double pj = 1.0;
    for (int t = 0; t < j; ++t) pj *= p;
    double p191j = 1.0;
    for (int t = 0; t < 191 - j; ++t) p191j *= p;
    double p2n = 1.0;
    for (int t = 0; t < 192; ++t) p2n *= p;
    double K = p / (1.0 - p2n);
    double cur = 6.0 * K * (pj + p191j) + (j == 0 ? 6.0 : 0.0);
    c[0] = cur;
    for (int i = 1; i < 96; ++i) {
        cur = (i == j ? 6.0 : 0.0) + p * cur;
        c[i] = cur;
    }
    double nxt = cur * (p / (p - 1.0));
    Wd[95 * 96 + j] = nxt;
    for (int i = 94; i >= 0; --i) {
        nxt = p * (nxt - c[i]);
        Wd[i * 96 + j] = nxt;
    }
}

__global__ void compute_M_kernel(const double* __restrict__ Wd, float* __restrict__ Mb) {
    int i = threadIdx.x;
    if (i >= 192) return;
    const double cw[8] = {1.0 / 384.0, 121.0 / 384.0, 235.0 / 384.0, 27.0 / 384.0,
                          27.0 / 384.0, 235.0 / 384.0, 121.0 / 384.0, 1.0 / 384.0};
    int ph = i & 1;
    int c = i >> 1;
    for (int t = 0; t < TAPS; ++t) {
        int j = c - 13 + t;
        double m = 0.0;
        if (j >= 0 && j < 96) {
            for (int tt = 0; tt < 4; ++tt) {
                int k = c + ph - 2 + tt;
                k = k < 0 ? 0 : (k > 95 ? 95 : k);
                m += cw[ph * 4 + tt] * Wd[k * 96 + j];
            }
        }
        Mb[i * TAPS + t] = (float)m;
    }
}

// ---------- shared device bodies (512 threads) ----------

// Z unit: 64 z-lines of 96 -> 192, contiguous along last axis.
__device__ __forceinline__ void z_unit(int u, const float* __restrict__ in,
                                       float* __restrict__ sIn /*64*97*/,
                                       float* __restrict__ sOut /*64*193*/) {
    int tid = threadIdx.x;
    size_t base = (size_t)u * 64;
    const float4* src4 = (const float4*)(in + base * 96);
#pragma unroll
    for (int i = 0; i < 3; ++i) {  // 1536 float4; 96%4==0 -> no pad-row cross
        int k4 = tid + i * 512;
        int row = k4 / 24;
        int c = (k4 % 24) * 4;
        float4 v = src4[k4];
        float* p = sIn + row * 97 + c;
        p[0] = v.x; p[1] = v.y; p[2] = v.z; p[3] = v.w;
    }
    __syncthreads();
    int lane = tid & 63, wave = tid >> 6;
    int c0 = wave * 12;
    const float* xl = sIn + lane * 97;
    float* op = sOut + lane * 193 + 2 * c0;
    float win[39];
#pragma unroll
    for (int k = 0; k < 39; ++k) win[k] = xl[clamp96(c0 - 13 + k)];
    if (wave >= 1 && wave <= 6) {  // interior c in [12,84): Toeplitz stencil
        float w0[TAPS], w1[TAPS];
#pragma unroll
        for (int t = 0; t < TAPS; ++t) { w0[t] = g_Mb[96 * TAPS + t]; w1[t] = g_Mb[97 * TAPS + t]; }
#pragma unroll
        for (int mi = 0; mi < 12; ++mi) {
            float a0 = 0.f, a1 = 0.f;
#pragma unroll
            for (int t = 0; t < TAPS; ++t) {
                float xv = win[mi + t];
                a0 = fmaf(w0[t], xv, a0);
                a1 = fmaf(w1[t], xv, a1);
            }
            op[2 * mi] = a0;
            op[2 * mi + 1] = a1;
        }
    } else {  // edge: exact table rows (wave-uniform address -> s_load)
#pragma unroll
        for (int mi = 0; mi < 12; ++mi) {
            int m = c0 + mi;
            int wb = __builtin_amdgcn_readfirstlane(m * 2 * TAPS);
            const float* wr = g_Mb + wb;
            float a0 = 0.f, a1 = 0.f;
#pragma unroll
            for (int t = 0; t < TAPS; ++t) {
                float xv = win[mi + t];
                a0 = fmaf(wr[t], xv, a0);
                a1 = fmaf(wr[TAPS + t], xv, a1);
            }
            op[2 * mi] = a0;
            op[2 * mi + 1] = a1;
        }
    }
    __syncthreads();
    float4* dst4 = (float4*)(g_bufA + base * 192);
#pragma unroll
    for (int i = 0; i < 6; ++i) {  // 3072 float4; 192%4==0
        int k4 = tid + i * 512;
        int row = k4 / 48;
        int c = (k4 % 48) * 4;
        const float* p = sOut + row * 193 + c;
        dst4[k4] = make_float4(p[0], p[1], p[2], p[3]);
    }
    // no trailing barrier needed: next unit writes sIn; all sIn reads were
    // fenced by the mid barrier, and sOut readers re-sync at next post-stage.
}

// Y/X unit: [O][96][INNER] -> [O][192][INNER], 64-col tile staged in LDS.
template <int INNER, int CT>
__device__ __forceinline__ void yx_unit(int u, const float* __restrict__ inb,
                                        float* __restrict__ outb,
                                        float* __restrict__ sY /*96*64*/) {
    int tid = threadIdx.x;
    int ct = u % CT;
    int o = u / CT;
    const float* src = inb + (size_t)o * 96 * INNER + (size_t)ct * 64;
    float* dst = outb + (size_t)o * 192 * INNER + (size_t)ct * 64;
#pragma unroll
    for (int i = 0; i < 3; ++i) {  // 1536 float4, block-level MLP
        int k4 = tid + i * 512;
        int row = k4 >> 4;
        int c4 = k4 & 15;
        float4 v = ((const float4*)(src + (size_t)row * INNER))[c4];
        ((float4*)(sY + row * 64))[c4] = v;
    }
    __syncthreads();
    int lane = tid & 63, wave = tid >> 6;
    int c0 = wave * 12;
    float win[39];
#pragma unroll
    for (int k = 0; k < 39; ++k) win[k] = sY[clamp96(c0 - 13 + k) * 64 + lane];
    if (wave >= 1 && wave <= 6) {
        float w0[TAPS], w1[TAPS];
#pragma unroll
        for (int t = 0; t < TAPS; ++t) { w0[t] = g_Mb[96 * TAPS + t]; w1[t] = g_Mb[97 * TAPS + t]; }
#pragma unroll
        for (int mi = 0; mi < 12; ++mi) {
            float a0 = 0.f, a1 = 0.f;
#pragma unroll
            for (int t = 0; t < TAPS; ++t) {
                float xv = win[mi + t];
                a0 = fmaf(w0[t], xv, a0);
                a1 = fmaf(w1[t], xv, a1);
            }
            int m = c0 + mi;
            dst[(size_t)(2 * m) * INNER + lane] = a0;
            dst[(size_t)(2 * m + 1) * INNER + lane] = a1;
        }
    } else {
#pragma unroll
        for (int mi = 0; mi < 12; ++mi) {
            int m = c0 + mi;
            int wb = __builtin_amdgcn_readfirstlane(m * 2 * TAPS);
            const float* wr = g_Mb + wb;
            float a0 = 0.f, a1 = 0.f;
#pragma unroll
            for (int t = 0; t < TAPS; ++t) {
                float xv = win[mi + t];
                a0 = fmaf(wr[t], xv, a0);
                a1 = fmaf(wr[TAPS + t], xv, a1);
            }
            dst[(size_t)(2 * m) * INNER + lane] = a0;
            dst[(size_t)(2 * m + 1) * INNER + lane] = a1;
        }
    }
    __syncthreads();  // protect sY before next unit restages
}

// ---------- fused cooperative kernel ----------
__global__ __launch_bounds__(512, 4) void fused_zyx(const float* __restrict__ in,
                                                    float* __restrict__ out) {
    __shared__ alignas(16) float sIn[64 * 97];
    __shared__ alignas(16) float sOut[64 * 193];
    cg::grid_group grid = cg::this_grid();
    for (int u = blockIdx.x; u < 864; u += gridDim.x) z_unit(u, in, sIn, sOut);
    grid.sync();
    for (int u = blockIdx.x; u < 576 * 3; u += gridDim.x) yx_unit<192, 3>(u, g_bufA, g_bufB, sIn);
    grid.sync();
    for (int u = blockIdx.x; u < 6 * 576; u += gridDim.x) yx_unit<36864, 576>(u, g_bufB, out, sIn);
}

// ---------- fallback (non-cooperative) ----------
__global__ __launch_bounds__(512) void zk(const float* __restrict__ in) {
    __shared__ alignas(16) float sIn[64 * 97];
    __shared__ alignas(16) float sOut[64 * 193];
    z_unit(blockIdx.x, in, sIn, sOut);
}
__global__ __launch_bounds__(512) void yk() {
    __shared__ alignas(16) float sY[96 * 64];
    yx_unit<192, 3>(blockIdx.x, g_bufA, g_bufB, sY);
}
__global__ __launch_bounds__(512) void xk(float* __restrict__ out) {
    __shared__ alignas(16) float sY[96 * 64];
    yx_unit<36864, 576>(blockIdx.x, g_bufB, out, sY);
}

extern "C" void kernel_launch(void* const* d_in, const int* in_sizes, int n_in,
                              void* d_out, int out_size, void* d_ws, size_t ws_size,
                              hipStream_t stream) {
    const float* x = (const float*)d_in[0];
    float* out = (float*)d_out;
    double* Wd;
    float* Mb;
    hipGetSymbolAddress((void**)&Wd, HIP_SYMBOL(g_Wd));
    hipGetSymbolAddress((void**)&Mb, HIP_SYMBOL(g_Mb));

    compute_Wd_kernel<<<1, 96, 0, stream>>>(Wd);
    compute_M_kernel<<<1, 192, 0, stream>>>(Wd, Mb);

    int occ = 0;
    hipError_t oe = hipOccupancyMaxActiveBlocksPerMultiprocessor(
        &occ, reinterpret_cast<const void*>(fused_zyx), 512, 0);
    bool done = false;
    if (oe == hipSuccess && occ > 0) {
        int grid = occ * 256;  // MI355X: 256 CUs; all blocks co-resident
        if (grid > 3456) grid = 3456;
        void* args[] = {(void*)&x, (void*)&out};
        if (hipLaunchCooperativeKernel(reinterpret_cast<const void*>(fused_zyx),
                                       dim3(grid), dim3(512), args, 0, stream) == hipSuccess)
            done = true;
    }
    if (!done) {  // non-cooperative fallback: same bodies, implicit global sync
        zk<<<864, 512, 0, stream>>>(x);
        yk<<<1728, 512, 0, stream>>>();
        xk<<<3456, 512, 0, stream>>>(out);
    }
}

// Round 6
// 310.046 us; speedup vs baseline: 2.4994x; 2.4994x over previous
//
#include <hip/hip_runtime.h>

// CubicSplineUpsampling: (2,3,96,96,96) f32 -> (2,3,192,192,192) f32.
//
// out_line(192) = M * in_line(96) per axis, M = U_clamped(192x96) . W(96x96),
// banded to 28 taps at j0=c-13. Interior rows (c in [12,84)) collapse to one
// Toeplitz 2x28 stencil (rows 96/97 of M; error <=1e-4 << tol 1.56e-2,
// validated R2-R5). Edge rows use exact table rows.
//
// R6: R5's fused coop kernel (514 us dispatch, 775 total) proved ~255 us of
// the timed window is NOT kernel execution: dispatch-boundary / graph-node
// overhead. (It also proved grid.sync() forces intermediates to HBM: 962 MB
// vs 446 ideal -> fusion reverted.) Back-fit: every split round ~= 250 gap +
// ~75-135 us of passes. So: cut dispatches 5 -> 3 by computing the M table at
// C++ COMPILE TIME (constexpr -> __constant__), deleting the Wd and M
// kernels. Pass bodies are byte-identical to R4 (best stable, 332 us).
// Decisive A/B: big drop => boundary overhead confirmed; ~5 us drop => H9
// dead, attack X-pass internals next.

#define TAPS 28

// ---------- compile-time M table ----------
struct MTab { float v[192 * TAPS]; };

static constexpr MTab make_M() {
    const double p = -0.26794919243112270647253365849413;  // sqrt(3)-2
    // incremental pole powers p^0..p^192 (keeps constexpr step count low)
    double pw[193] = {};
    pw[0] = 1.0;
    for (int i = 1; i <= 192; ++i) pw[i] = pw[i - 1] * p;
    double Wd[96][96] = {};
    for (int j = 0; j < 96; ++j) {
        double c[96] = {};
        double K = p / (1.0 - pw[192]);
        double cur = 6.0 * K * (pw[j] + pw[191 - j]) + (j == 0 ? 6.0 : 0.0);
        c[0] = cur;
        for (int i = 1; i < 96; ++i) {
            cur = (i == j ? 6.0 : 0.0) + p * cur;
            c[i] = cur;
        }
        double nxt = cur * (p / (p - 1.0));
        Wd[95][j] = nxt;
        for (int i = 94; i >= 0; --i) {
            nxt = p * (nxt - c[i]);
            Wd[i][j] = nxt;
        }
    }
    MTab M = {};
    const double cw[8] = {1.0 / 384.0, 121.0 / 384.0, 235.0 / 384.0, 27.0 / 384.0,
                          27.0 / 384.0, 235.0 / 384.0, 121.0 / 384.0, 1.0 / 384.0};
    for (int i = 0; i < 192; ++i) {
        int ph = i & 1;
        int cc = i >> 1;
        for (int t = 0; t < TAPS; ++t) {
            int j = cc - 13 + t;
            double m = 0.0;
            if (j >= 0 && j < 96) {
                for (int tt = 0; tt < 4; ++tt) {
                    int k = cc + ph - 2 + tt;
                    k = k < 0 ? 0 : (k > 95 ? 95 : k);
                    m += cw[ph * 4 + tt] * Wd[k][j];
                }
            }
            M.v[i * TAPS + t] = (float)m;
        }
    }
    return M;
}

static constexpr MTab h_M = make_M();
__device__ __constant__ MTab g_M = h_M;  // 21.5 KB, wave-uniform reads -> s_load

__device__ alignas(16) float g_bufA[6 * 96 * 96 * 192];   // after Z
__device__ alignas(16) float g_bufB[6 * 96 * 192 * 192];  // after Y

__device__ __forceinline__ int clamp96(int j) { return j < 0 ? 0 : (j > 95 ? 95 : j); }

// ---------- Z pass (R4 body, weights from __constant__) ----------
__global__ __launch_bounds__(512) void pass_z(const float* __restrict__ in,
                                              float* __restrict__ out) {
    __shared__ float s_in[64 * 97];
    __shared__ float s_out[64 * 193];
    const float* Mb = g_M.v;
    float w0[TAPS], w1[TAPS];
#pragma unroll
    for (int t = 0; t < TAPS; ++t) {
        w0[t] = Mb[96 * TAPS + t];
        w1[t] = Mb[97 * TAPS + t];
    }
    size_t base = (size_t)blockIdx.x * 64;
    const float* src = in + base * 96;
    int tid = threadIdx.x;
    for (int k = tid; k < 64 * 96; k += 512)
        s_in[(k / 96) * 97 + (k % 96)] = src[k];
    __syncthreads();

    int lane = tid & 63;
    int wave = tid >> 6;
    int c0 = wave * 12;
    const float* xl = s_in + lane * 97;
    float* op = s_out + lane * 193 + 2 * c0;
    float win[39];
#pragma unroll
    for (int k = 0; k < 39; ++k) win[k] = xl[clamp96(c0 - 13 + k)];

    if (wave >= 1 && wave <= 6) {  // interior c in [12,84): Toeplitz stencil
#pragma unroll
        for (int mi = 0; mi < 12; ++mi) {
            float a0 = 0.f, a1 = 0.f;
#pragma unroll
            for (int t = 0; t < TAPS; ++t) {
                float xv = win[mi + t];
                a0 = fmaf(w0[t], xv, a0);
                a1 = fmaf(w1[t], xv, a1);
            }
            op[2 * mi] = a0;
            op[2 * mi + 1] = a1;
        }
    } else {  // edge: exact table rows (wave-uniform -> s_load)
#pragma unroll
        for (int mi = 0; mi < 12; ++mi) {
            int m = c0 + mi;
            int wb = __builtin_amdgcn_readfirstlane(m * 2 * TAPS);
            const float* wr = Mb + wb;
            float a0 = 0.f, a1 = 0.f;
#pragma unroll
            for (int t = 0; t < TAPS; ++t) {
                float xv = win[mi + t];
                a0 = fmaf(wr[t], xv, a0);
                a1 = fmaf(wr[TAPS + t], xv, a1);
            }
            op[2 * mi] = a0;
            op[2 * mi + 1] = a1;
        }
    }
    __syncthreads();
    float* dst = out + base * 192;
    for (int k = tid; k < 64 * 192; k += 512)
        dst[k] = s_out[(k / 192) * 193 + (k % 192)];
}

// ---------- Y/X staged pass (R4 body, weights from __constant__) ----------
// in [O][96][INNER] -> out [O][192][INNER]. Block = (o, 64-col tile): stage
// 96x64 slab (24KB LDS, 1536 independent float4 loads), 4 waves x 24 c's
// compute from LDS, wave-wide 256B stores direct to global.
template <int INNER>
__global__ __launch_bounds__(256) void pass_staged(const float* __restrict__ in,
                                                   float* __restrict__ out) {
    constexpr int CT = INNER / 64;
    __shared__ float s[96 * 64];
    const float* Mb = g_M.v;
    int tid = threadIdx.x;
    int ct = blockIdx.x % CT;
    int o = blockIdx.x / CT;
    const float* src = in + (size_t)o * 96 * INNER + (size_t)ct * 64;
    float* dst = out + (size_t)o * 192 * INNER + (size_t)ct * 64;

#pragma unroll
    for (int it = 0; it < 6; ++it) {  // 1536 float4, block-level MLP
        int k = tid + it * 256;
        int row = k >> 4;
        int c4 = k & 15;
        float4 v = *(const float4*)(src + (size_t)row * INNER + c4 * 4);
        *(float4*)(&s[row * 64 + c4 * 4]) = v;
    }
    __syncthreads();

    int col = tid & 63;
    int cq = tid >> 6;
    int c0 = cq * 24;

    float win[51];
#pragma unroll
    for (int k = 0; k < 51; ++k) win[k] = s[clamp96(c0 - 13 + k) * 64 + col];

    if (cq == 1 || cq == 2) {  // interior c in [24,72): Toeplitz stencil
        float w0[TAPS], w1[TAPS];
#pragma unroll
        for (int t = 0; t < TAPS; ++t) {
            w0[t] = Mb[96 * TAPS + t];
            w1[t] = Mb[97 * TAPS + t];
        }
#pragma unroll
        for (int mi = 0; mi < 24; ++mi) {
            float a0 = 0.f, a1 = 0.f;
#pragma unroll
            for (int t = 0; t < TAPS; ++t) {
                float xv = win[mi + t];
                a0 = fmaf(w0[t], xv, a0);
                a1 = fmaf(w1[t], xv, a1);
            }
            int m = c0 + mi;
            dst[(size_t)(2 * m) * INNER + col] = a0;
            dst[(size_t)(2 * m + 1) * INNER + col] = a1;
        }
    } else {  // edge waves: exact table rows
#pragma unroll
        for (int mi = 0; mi < 24; ++mi) {
            int m = c0 + mi;
            int wb = __builtin_amdgcn_readfirstlane(m * 2 * TAPS);
            const float* wr = Mb + wb;
            float a0 = 0.f, a1 = 0.f;
#pragma unroll
            for (int t = 0; t < TAPS; ++t) {
                float xv = win[mi + t];
                a0 = fmaf(wr[t], xv, a0);
                a1 = fmaf(wr[TAPS + t], xv, a1);
            }
            dst[(size_t)(2 * m) * INNER + col] = a0;
            dst[(size_t)(2 * m + 1) * INNER + col] = a1;
        }
    }
}

extern "C" void kernel_launch(void* const* d_in, const int* in_sizes, int n_in,
                              void* d_out, int out_size, void* d_ws, size_t ws_size,
                              hipStream_t stream) {
    const float* x = (const float*)d_in[0];
    float* out = (float*)d_out;
    float *bufA, *bufB;
    hipGetSymbolAddress((void**)&bufA, HIP_SYMBOL(g_bufA));
    hipGetSymbolAddress((void**)&bufB, HIP_SYMBOL(g_bufB));

    // Z: 6*96*96 = 55296 lines / 64 per block
    pass_z<<<864, 512, 0, stream>>>(x, bufA);
    // Y: O = 6*96 = 576, CT = 192/64 = 3 -> 1728 blocks
    pass_staged<192><<<1728, 256, 0, stream>>>(bufA, bufB);
    // X: O = 6, CT = 36864/64 = 576 -> 3456 blocks
    pass_staged<36864><<<3456, 256, 0, stream>>>(bufB, out);
}

// Round 7
// 284.471 us; speedup vs baseline: 2.7241x; 1.0899x over previous
//
#include <hip/hip_runtime.h>

// CubicSplineUpsampling: (2,3,96,96,96) f32 -> (2,3,192,192,192) f32.
//
// out_line(192) = M * in_line(96) per axis, M = U_clamped(192x96) . W(96x96),
// banded to 28 taps at j0=c-13. Interior rows (c in [12,84)) collapse to one
// Toeplitz 2x28 stencil (rows 96/97 of M; error <=1e-4 << tol, validated
// R2-R6). Edge rows use exact table rows. M computed at C++ compile time
// into __constant__ (R6, saved 2 dispatches).
//
// R7: boundary overhead measured at ~11 us/dispatch (R6: -2 dispatches =
// -22 us). Remaining ~280 us is pass time vs 71 us HBM floor. Kill the bufA
// round-trip: fuse Z into Y per-block (NO grid.sync -- R5 showed coop fusion
// forces 962 MB traffic). Block = (o, a, 64-wide Z-tile): stage [96 b][64 z]
// input band (24 KB), Z-transform in-block into s_mid[96][65] (wave-uniform
// m, window-in-regs, stencil/table split), then R6's verified Y phase from
// s_mid, writing bufB directly. Deletes 1 dispatch + 85 MB HBM. X pass
// byte-identical to R6 (control).

#define TAPS 28

// ---------- compile-time M table ----------
struct MTab { float v[192 * TAPS]; };

static constexpr MTab make_M() {
    const double p = -0.26794919243112270647253365849413;  // sqrt(3)-2
    double pw[193] = {};
    pw[0] = 1.0;
    for (int i = 1; i <= 192; ++i) pw[i] = pw[i - 1] * p;
    double Wd[96][96] = {};
    for (int j = 0; j < 96; ++j) {
        double c[96] = {};
        double K = p / (1.0 - pw[192]);
        double cur = 6.0 * K * (pw[j] + pw[191 - j]) + (j == 0 ? 6.0 : 0.0);
        c[0] = cur;
        for (int i = 1; i < 96; ++i) {
            cur = (i == j ? 6.0 : 0.0) + p * cur;
            c[i] = cur;
        }
        double nxt = cur * (p / (p - 1.0));
        Wd[95][j] = nxt;
        for (int i = 94; i >= 0; --i) {
            nxt = p * (nxt - c[i]);
            Wd[i][j] = nxt;
        }
    }
    MTab M = {};
    const double cw[8] = {1.0 / 384.0, 121.0 / 384.0, 235.0 / 384.0, 27.0 / 384.0,
                          27.0 / 384.0, 235.0 / 384.0, 121.0 / 384.0, 1.0 / 384.0};
    for (int i = 0; i < 192; ++i) {
        int ph = i & 1;
        int cc = i >> 1;
        for (int t = 0; t < TAPS; ++t) {
            int j = cc - 13 + t;
            double m = 0.0;
            if (j >= 0 && j < 96) {
                for (int tt = 0; tt < 4; ++tt) {
                    int k = cc + ph - 2 + tt;
                    k = k < 0 ? 0 : (k > 95 ? 95 : k);
                    m += cw[ph * 4 + tt] * Wd[k][j];
                }
            }
            M.v[i * TAPS + t] = (float)m;
        }
    }
    return M;
}

static constexpr MTab h_M = make_M();
__device__ __constant__ MTab g_M = h_M;  // 21.5 KB; wave-uniform reads -> s_load

__device__ alignas(16) float g_bufB[6 * 96 * 192 * 192];  // after fused Z+Y

__device__ __forceinline__ int clamp96(int j) { return j < 0 ? 0 : (j > 95 ? 95 : j); }

// ---------- fused Z+Y pass ----------
// Block = (o*96+a, Z-tile w of 3). in [oa][96 b][96 z] -> out [oa][192 b][64 Z cols].
// Phase 1: stage input z-band s_in[96 b][64 zi], zi -> z = clamp(32w-13+zi).
// Phase 2: Z-transform. 8 waves x 4 m each (m_l = 4*wv+mi, wave-uniform);
//   lane = b (lanes<32 also handle b+64); window win[31] = s_in[b][4wv..+31]
//   (j0_local for m_l is exactly m_l since j0 = m>>... = m_l + jlo offset);
//   outputs s_mid[b][2*m_l(+1)]. Stride-65 rows => all patterns <=2-way banks.
// Phase 3: Y-transform (R6 pass_z compute shape): wave wv owns c in
//   [12wv,12wv+12), win[39] over s_mid rows, writes out rows 2c,2c+1 cols
//   [64w,64w+64) coalesced 256B.
__global__ __launch_bounds__(512) void pass_zy(const float* __restrict__ in,
                                               float* __restrict__ out) {
    __shared__ float s_in[96 * 65];
    __shared__ float s_mid[96 * 65];
    int tid = threadIdx.x;
    int w = blockIdx.x % 3;
    int oa = blockIdx.x / 3;
    const float* src = in + (size_t)oa * 96 * 96;
    float* dst = out + (size_t)oa * 192 * 192 + 64 * w;
    int jlo = 32 * w - 13;

    // Phase 1: stage [96][64] clamped z-band (coalesced: lanes -> consecutive z)
#pragma unroll
    for (int it = 0; it < 12; ++it) {
        int k = tid + it * 512;
        int b = k >> 6;
        int zi = k & 63;
        s_in[b * 65 + zi] = src[b * 96 + clamp96(jlo + zi)];
    }
    __syncthreads();

    int lane = tid & 63;
    int wv = tid >> 6;

    // Phase 2: Z-transform into s_mid
    {
        float w0[TAPS], w1[TAPS];
#pragma unroll
        for (int t = 0; t < TAPS; ++t) {
            w0[t] = g_M.v[96 * TAPS + t];
            w1[t] = g_M.v[97 * TAPS + t];
        }
        float win1[31], win2[31];
        const float* p1 = s_in + lane * 65 + 4 * wv;
#pragma unroll
        for (int k = 0; k < 31; ++k) win1[k] = p1[k];
        if (lane < 32) {
            const float* p2 = s_in + (lane + 64) * 65 + 4 * wv;
#pragma unroll
            for (int k = 0; k < 31; ++k) win2[k] = p2[k];
        }
        float* q1 = s_mid + lane * 65 + 8 * wv;
        float* q2 = s_mid + (lane + 64) * 65 + 8 * wv;
#pragma unroll
        for (int mi = 0; mi < 4; ++mi) {
            int m_g = 32 * w + 4 * wv + mi;  // wave-uniform
            float a0 = 0.f, a1 = 0.f, c0v = 0.f, c1v = 0.f;
            if (m_g >= 12 && m_g < 84) {  // interior: Toeplitz stencil
#pragma unroll
                for (int t = 0; t < TAPS; ++t) {
                    a0 = fmaf(w0[t], win1[mi + t], a0);
                    a1 = fmaf(w1[t], win1[mi + t], a1);
                }
                if (lane < 32) {
#pragma unroll
                    for (int t = 0; t < TAPS; ++t) {
                        c0v = fmaf(w0[t], win2[mi + t], c0v);
                        c1v = fmaf(w1[t], win2[mi + t], c1v);
                    }
                }
            } else {  // edge: exact table row (wave-uniform -> s_load)
                int wb = __builtin_amdgcn_readfirstlane(m_g * 2 * TAPS);
                const float* wr = g_M.v + wb;
#pragma unroll
                for (int t = 0; t < TAPS; ++t) {
                    a0 = fmaf(wr[t], win1[mi + t], a0);
                    a1 = fmaf(wr[TAPS + t], win1[mi + t], a1);
                }
                if (lane < 32) {
#pragma unroll
                    for (int t = 0; t < TAPS; ++t) {
                        c0v = fmaf(wr[t], win2[mi + t], c0v);
                        c1v = fmaf(wr[TAPS + t], win2[mi + t], c1v);
                    }
                }
            }
            q1[2 * mi] = a0;
            q1[2 * mi + 1] = a1;
            if (lane < 32) {
                q2[2 * mi] = c0v;
                q2[2 * mi + 1] = c1v;
            }
        }
    }
    __syncthreads();

    // Phase 3: Y-transform (R6-validated shape), wave wv -> c in [12wv,12wv+12)
    {
        int c0 = 12 * wv;
        float win[39];
#pragma unroll
        for (int k = 0; k < 39; ++k) win[k] = s_mid[clamp96(c0 - 13 + k) * 65 + lane];
        if (wv >= 1 && wv <= 6) {  // interior c in [12,84)
            float w0[TAPS], w1[TAPS];
#pragma unroll
            for (int t = 0; t < TAPS; ++t) {
                w0[t] = g_M.v[96 * TAPS + t];
                w1[t] = g_M.v[97 * TAPS + t];
            }
#pragma unroll
            for (int mi = 0; mi < 12; ++mi) {
                float a0 = 0.f, a1 = 0.f;
#pragma unroll
                for (int t = 0; t < TAPS; ++t) {
                    float xv = win[mi + t];
                    a0 = fmaf(w0[t], xv, a0);
                    a1 = fmaf(w1[t], xv, a1);
                }
                int c = c0 + mi;
                dst[(size_t)(2 * c) * 192 + lane] = a0;
                dst[(size_t)(2 * c + 1) * 192 + lane] = a1;
            }
        } else {  // edge waves: exact table rows
#pragma unroll
            for (int mi = 0; mi < 12; ++mi) {
                int c = c0 + mi;
                int wb = __builtin_amdgcn_readfirstlane(c * 2 * TAPS);
                const float* wr = g_M.v + wb;
                float a0 = 0.f, a1 = 0.f;
#pragma unroll
                for (int t = 0; t < TAPS; ++t) {
                    float xv = win[mi + t];
                    a0 = fmaf(wr[t], xv, a0);
                    a1 = fmaf(wr[TAPS + t], xv, a1);
                }
                dst[(size_t)(2 * c) * 192 + lane] = a0;
                dst[(size_t)(2 * c + 1) * 192 + lane] = a1;
            }
        }
    }
}

// ---------- X staged pass (byte-identical to R6 body) ----------
template <int INNER>
__global__ __launch_bounds__(256) void pass_staged(const float* __restrict__ in,
                                                   float* __restrict__ out) {
    constexpr int CT = INNER / 64;
    __shared__ float s[96 * 64];
    const float* Mb = g_M.v;
    int tid = threadIdx.x;
    int ct = blockIdx.x % CT;
    int o = blockIdx.x / CT;
    const float* src = in + (size_t)o * 96 * INNER + (size_t)ct * 64;
    float* dst = out + (size_t)o * 192 * INNER + (size_t)ct * 64;

#pragma unroll
    for (int it = 0; it < 6; ++it) {
        int k = tid + it * 256;
        int row = k >> 4;
        int c4 = k & 15;
        float4 v = *(const float4*)(src + (size_t)row * INNER + c4 * 4);
        *(float4*)(&s[row * 64 + c4 * 4]) = v;
    }
    __syncthreads();

    int col = tid & 63;
    int cq = tid >> 6;
    int c0 = cq * 24;

    float win[51];
#pragma unroll
    for (int k = 0; k < 51; ++k) win[k] = s[clamp96(c0 - 13 + k) * 64 + col];

    if (cq == 1 || cq == 2) {
        float w0[TAPS], w1[TAPS];
#pragma unroll
        for (int t = 0; t < TAPS; ++t) {
            w0[t] = Mb[96 * TAPS + t];
            w1[t] = Mb[97 * TAPS + t];
        }
#pragma unroll
        for (int mi = 0; mi < 24; ++mi) {
            float a0 = 0.f, a1 = 0.f;
#pragma unroll
            for (int t = 0; t < TAPS; ++t) {
                float xv = win[mi + t];
                a0 = fmaf(w0[t], xv, a0);
                a1 = fmaf(w1[t], xv, a1);
            }
            int m = c0 + mi;
            dst[(size_t)(2 * m) * INNER + col] = a0;
            dst[(size_t)(2 * m + 1) * INNER + col] = a1;
        }
    } else {
#pragma unroll
        for (int mi = 0; mi < 24; ++mi) {
            int m = c0 + mi;
            int wb = __builtin_amdgcn_readfirstlane(m * 2 * TAPS);
            const float* wr = Mb + wb;
            float a0 = 0.f, a1 = 0.f;
#pragma unroll
            for (int t = 0; t < TAPS; ++t) {
                float xv = win[mi + t];
                a0 = fmaf(wr[t], xv, a0);
                a1 = fmaf(wr[TAPS + t], xv, a1);
            }
            dst[(size_t)(2 * m) * INNER + col] = a0;
            dst[(size_t)(2 * m + 1) * INNER + col] = a1;
        }
    }
}

extern "C" void kernel_launch(void* const* d_in, const int* in_sizes, int n_in,
                              void* d_out, int out_size, void* d_ws, size_t ws_size,
                              hipStream_t stream) {
    const float* x = (const float*)d_in[0];
    float* out = (float*)d_out;
    float* bufB;
    hipGetSymbolAddress((void**)&bufB, HIP_SYMBOL(g_bufB));

    // fused Z+Y: (6*96 oa) x 3 Z-tiles = 1728 blocks, 512 threads
    pass_zy<<<1728, 512, 0, stream>>>(x, bufB);
    // X: O = 6, CT = 36864/64 = 576 -> 3456 blocks
    pass_staged<36864><<<3456, 256, 0, stream>>>(bufB, out);
}